// Round 8
// baseline (322.786 us; speedup 1.0000x reference)
//
#include <hip/hip_runtime.h>
#include <math.h>

#define BB   16
#define HHH  56
#define WWW  56
#define LL   3136      // 56*56
#define DI_  128
#define KK   4
#define NCH  98        // chunks per (b,k)
#define CS   32        // chunk size; NCH*CS == LL

// workspace layout (floats)
#define OFF_XI   ((size_t)0)           // B*L*DI ; reused as YSUM
#define OFF_ZS   ((size_t)6422528)
#define OFF_XC   ((size_t)12845056)    // xc; also hosts Whi/Wlo BEFORE k_conv writes it
#define OFF_XDN  ((size_t)19267584)    // B*L*32
#define OFF_PA   ((size_t)20873216)
#define OFF_HL   ((size_t)21676032)
#define OFF_H0   ((size_t)22478848)
#define OFF_CWT  ((size_t)23281664)    // 9*128 transposed conv weights

typedef short s16x8 __attribute__((ext_vector_type(8)));
typedef float f32x4 __attribute__((ext_vector_type(4)));

__device__ __forceinline__ float sigmoidf_(float x) { return 1.0f / (1.0f + __expf(-x)); }
__device__ __forceinline__ float softplus_(float x) {
    return fmaxf(x, 0.0f) + __logf(1.0f + __expf(-fabsf(x)));
}

// split f into bf16 hi/lo (RNE)
__device__ __forceinline__ void bf16split(float f, short* hi, short* lo) {
    unsigned u = __float_as_uint(f);
    unsigned r = u + 0x7FFFu + ((u >> 16) & 1u);
    *hi = (short)(r >> 16);
    float hf = __uint_as_float(r & 0xFFFF0000u);
    float l  = f - hf;
    unsigned u2 = __float_as_uint(l);
    unsigned r2 = u2 + 0x7FFFu + ((u2 >> 16) & 1u);
    *lo = (short)(r2 >> 16);
}

// ---------------- Kernel W: pre-split in_proj weights + transpose conv weights ----------------
__global__ __launch_bounds__(256) void k_wsplit(const float* __restrict__ Wp,
                                                const float* __restrict__ cw,
                                                short* __restrict__ Whi,
                                                short* __restrict__ Wlo,
                                                float* __restrict__ cwT)
{
    const int idx = blockIdx.x * 256 + threadIdx.x;
    if (idx < 256 * 128) {
        short h, l;
        bf16split(Wp[idx], &h, &l);
        Whi[idx] = h;
        Wlo[idx] = l;
    }
    if (idx < 9 * 128) {
        const int t = idx >> 7;
        const int d = idx & 127;
        cwT[t * 128 + d] = cw[d * 9 + t];
    }
}

// ---------------- Kernel A: in_proj GEMM via bf16x3 MFMA ----------------
#define APAD 136   // 128 + 8 shorts row pad
__global__ __launch_bounds__(256) void k_inproj(const float* __restrict__ x,
                                                const short* __restrict__ Whi,
                                                const short* __restrict__ Wlo,
                                                float* __restrict__ xi,
                                                float* __restrict__ zs)
{
    __shared__ short Ahi[64 * APAD];
    __shared__ short Alo[64 * APAD];
    const int tid  = threadIdx.x;
    const int row0 = blockIdx.x * 64;

#pragma unroll
    for (int i = 0; i < 8; ++i) {
        const int idx4 = i * 256 + tid;
        const int row  = idx4 >> 5;
        const int k4   = (idx4 & 31) * 4;
        float4 v = *(const float4*)&x[(size_t)(row0 + row) * 128 + k4];
        const float f[4] = {v.x, v.y, v.z, v.w};
#pragma unroll
        for (int j = 0; j < 4; ++j) {
            short h, l;
            bf16split(f[j], &h, &l);
            Ahi[row * APAD + k4 + j] = h;
            Alo[row * APAD + k4 + j] = l;
        }
    }
    __syncthreads();

    const int w    = tid >> 6;
    const int lane = tid & 63;
    const int lr   = lane & 15;
    const int lk   = (lane >> 4) * 8;

    for (int cg = 0; cg < 4; ++cg) {
        const int col0 = cg * 64 + w * 16;
        s16x8 bhi[4], blo[4];
#pragma unroll
        for (int ks = 0; ks < 4; ++ks) {
            const size_t wo = (size_t)(col0 + lr) * 128 + ks * 32 + lk;
            bhi[ks] = *(const s16x8*)&Whi[wo];
            blo[ks] = *(const s16x8*)&Wlo[wo];
        }
#pragma unroll
        for (int rt = 0; rt < 4; ++rt) {
            f32x4 acc = {0.f, 0.f, 0.f, 0.f};
#pragma unroll
            for (int ks = 0; ks < 4; ++ks) {
                const int ao = (rt * 16 + lr) * APAD + ks * 32 + lk;
                s16x8 ahi = *(const s16x8*)&Ahi[ao];
                s16x8 alo = *(const s16x8*)&Alo[ao];
                acc = __builtin_amdgcn_mfma_f32_16x16x32_bf16(alo, bhi[ks], acc, 0, 0, 0);
                acc = __builtin_amdgcn_mfma_f32_16x16x32_bf16(ahi, blo[ks], acc, 0, 0, 0);
                acc = __builtin_amdgcn_mfma_f32_16x16x32_bf16(ahi, bhi[ks], acc, 0, 0, 0);
            }
            const int col = col0 + lr;
#pragma unroll
            for (int j = 0; j < 4; ++j) {
                const size_t row = row0 + rt * 16 + (lane >> 4) * 4 + j;
                const float v = acc[j];
                if (col < 128) {
                    xi[row * 128 + col] = v;
                } else {
                    zs[row * 128 + (col - 128)] = v * sigmoidf_(v);
                }
            }
        }
    }
}

// ---------------- Kernel B: depthwise conv, float4 x 4 rows, XCD-swizzled ----------------
__global__ __launch_bounds__(256) void k_conv4(const float* __restrict__ xi,
                                               const float* __restrict__ cwT,
                                               const float* __restrict__ cb,
                                               float* __restrict__ xc)
{
    const int wid = (blockIdx.x & 7) * 196 + (blockIdx.x >> 3);   // 1568 = 8*196
    const int idx = wid * 256 + threadIdx.x;
    const int d0  = (idx & 31) * 4;
    int rest = idx >> 5;
    const int w  = rest % WWW;
    rest /= WWW;
    const int hq = rest % 14;
    const int b  = rest / 14;
    const int h0 = hq * 4;

    float4 wt[9];
#pragma unroll
    for (int t = 0; t < 9; ++t) wt[t] = *(const float4*)&cwT[t * 128 + d0];
    const float4 bias = *(const float4*)&cb[d0];

    float4 a0 = bias, a1 = bias, a2 = bias, a3 = bias;
    const float* base = &xi[(size_t)b * LL * 128 + d0];
#pragma unroll
    for (int dr = -1; dr <= 4; ++dr) {
        const int hh = h0 + dr;
        if (hh < 0 || hh >= HHH) continue;
#pragma unroll
        for (int dc = -1; dc <= 1; ++dc) {
            const int ww = w + dc;
            if (ww < 0 || ww >= WWW) continue;
            const float4 v = *(const float4*)&base[(size_t)(hh * WWW + ww) * 128];
#pragma unroll
            for (int r = 0; r < 4; ++r) {
                const int tap = dr - r;
                if (tap < -1 || tap > 1) continue;
                const float4 wv = wt[(tap + 1) * 3 + (dc + 1)];
                float4* a = (r == 0) ? &a0 : (r == 1) ? &a1 : (r == 2) ? &a2 : &a3;
                a->x = fmaf(v.x, wv.x, a->x);
                a->y = fmaf(v.y, wv.y, a->y);
                a->z = fmaf(v.z, wv.z, a->z);
                a->w = fmaf(v.w, wv.w, a->w);
            }
        }
    }
    float4 av[4] = {a0, a1, a2, a3};
#pragma unroll
    for (int r = 0; r < 4; ++r) {
        float4 o;
        o.x = av[r].x * sigmoidf_(av[r].x);
        o.y = av[r].y * sigmoidf_(av[r].y);
        o.z = av[r].z * sigmoidf_(av[r].z);
        o.w = av[r].w * sigmoidf_(av[r].w);
        *(float4*)&xc[((size_t)b * LL + (h0 + r) * WWW + w) * 128 + d0] = o;
    }
}

// ---------------- Kernel C: projection in natural order ----------------
__global__ __launch_bounds__(256) void k_projN(const float* __restrict__ xc,
                                               const float* __restrict__ xpw,
                                               float* __restrict__ xdn)
{
    __shared__ float xs[64 * 129];
    __shared__ float wl[24 * 128];
    const int tid = threadIdx.x;
    const int b   = blockIdx.x / 49;
    const int p0  = (blockIdx.x % 49) * 64;

    for (int i = tid; i < 24 * 128; i += 256) wl[i] = xpw[i];

#pragma unroll
    for (int i = 0; i < 8; ++i) {
        const int idx4 = i * 256 + tid;
        const int row  = idx4 >> 5;
        const int d4   = (idx4 & 31) * 4;
        float4 v = *(const float4*)&xc[((size_t)b * LL + p0 + row) * 128 + d4];
        xs[row * 129 + d4 + 0] = v.x;
        xs[row * 129 + d4 + 1] = v.y;
        xs[row * 129 + d4 + 2] = v.z;
        xs[row * 129 + d4 + 3] = v.w;
    }
    __syncthreads();

    const int ks   = tid >> 6;
    const int lane = tid & 63;
    float a0 = 0.f, a1 = 0.f, a2 = 0.f, a3 = 0.f, a4 = 0.f, a5 = 0.f;
    const float* wb = &wl[ks * 6 * 128];
#pragma unroll 4
    for (int d = 0; d < 128; ++d) {
        const float xv = xs[lane * 129 + d];
        a0 = fmaf(xv, wb[0 * 128 + d], a0);
        a1 = fmaf(xv, wb[1 * 128 + d], a1);
        a2 = fmaf(xv, wb[2 * 128 + d], a2);
        a3 = fmaf(xv, wb[3 * 128 + d], a3);
        a4 = fmaf(xv, wb[4 * 128 + d], a4);
        a5 = fmaf(xv, wb[5 * 128 + d], a5);
    }
    float* o = &xdn[((size_t)(b * LL + p0 + lane)) * 32 + ks * 8];
    o[0] = a0; o[1] = a1; o[2] = a2; o[3] = a3; o[4] = a4; o[5] = a5;
}

// ---------------- Scan pass 1: merged direction pairs, interleaved chains ----------------
__global__ __launch_bounds__(128) void k_scan1m(const float* __restrict__ xc,
                                                const float* __restrict__ xdn,
                                                const float* __restrict__ dtw_g,
                                                const float* __restrict__ dtb_g,
                                                const float* __restrict__ alog,
                                                float* __restrict__ Pa,
                                                float* __restrict__ Hl)
{
    __shared__ float xds[CS * 16];
    const int mode = blockIdx.x / (BB * NCH);
    const int rem  = blockIdx.x % (BB * NCH);
    const int b = rem / NCH;
    const int c = rem % NCH;
    const int d = threadIdx.x;
    const int c2 = NCH - 1 - c;
    const int l0a = c * CS;
    const int kA = mode * 2;
    const int kB = kA + 1;
    const int bkA = b * 4 + kA, bkB = b * 4 + kB;

    const float* xcb  = &xc[(size_t)b * LL * 128];
    const float* base = &xdn[(size_t)b * LL * 32];

    {
        const int row = d >> 2;
        const int q   = (d & 3) * 4;
        int prow;
        if (mode == 0) prow = l0a + row;
        else { const int l = l0a + row; prow = (l % HHH) * WWW + (l / HHH); }
        *(float4*)&xds[row * 16 + q] = *(const float4*)&base[(size_t)prow * 32 + mode * 16 + q];
    }
    __syncthreads();

    int pj[CS];
    if (mode == 0) {
#pragma unroll
        for (int i = 0; i < CS; ++i) pj[i] = l0a + i;
    } else {
#pragma unroll
        for (int i = 0; i < CS; ++i) {
            const int l = l0a + i;
            pj[i] = (l % HHH) * WWW + (l / HHH);
        }
    }
    float xv[CS];
#pragma unroll
    for (int i = 0; i < CS; ++i) xv[i] = xcb[(size_t)pj[i] * 128 + d];

    const float A0 = dtw_g[(kA * 128 + d) * 4 + 0];
    const float A1 = dtw_g[(kA * 128 + d) * 4 + 1];
    const float A2 = dtw_g[(kA * 128 + d) * 4 + 2];
    const float A3 = dtw_g[(kA * 128 + d) * 4 + 3];
    const float Ab = dtb_g[kA * 128 + d];
    const float An = -__expf(alog[kA * 128 + d]);
    const float B0 = dtw_g[(kB * 128 + d) * 4 + 0];
    const float B1 = dtw_g[(kB * 128 + d) * 4 + 1];
    const float B2 = dtw_g[(kB * 128 + d) * 4 + 2];
    const float B3 = dtw_g[(kB * 128 + d) * 4 + 3];
    const float Bb = dtb_g[kB * 128 + d];
    const float Bn = -__expf(alog[kB * 128 + d]);

    float PA = 1.0f, hA = 0.0f, PB = 1.0f, hB = 0.0f;
#pragma unroll
    for (int i = 0; i < CS; ++i) {
        const int j = CS - 1 - i;
        const float* rA = &xds[i * 16];
        const float* rB = &xds[j * 16 + 8];
        const float drawA = fmaf(rA[0], A0, fmaf(rA[1], A1, fmaf(rA[2], A2, fmaf(rA[3], A3, Ab))));
        const float drawB = fmaf(rB[0], B0, fmaf(rB[1], B1, fmaf(rB[2], B2, fmaf(rB[3], B3, Bb))));
        const float dtA = softplus_(drawA);
        const float dtB = softplus_(drawB);
        const float dAA = __expf(dtA * An);
        const float dAB = __expf(dtB * Bn);
        PA *= dAA;
        PB *= dAB;
        hA = fmaf(dAA, hA, dtA * rA[4] * xv[i]);
        hB = fmaf(dAB, hB, dtB * rB[4] * xv[j]);
    }
    Pa[((size_t)bkA * NCH + c)  * 128 + d] = PA;
    Hl[((size_t)bkA * NCH + c)  * 128 + d] = hA;
    Pa[((size_t)bkB * NCH + c2) * 128 + d] = PB;
    Hl[((size_t)bkB * NCH + c2) * 128 + d] = hB;
}

// ---------------- Scan pass 2: combine chunk summaries ----------------
__global__ __launch_bounds__(128) void k_scan2(const float* __restrict__ Pa,
                                               const float* __restrict__ Hl,
                                               float* __restrict__ H0)
{
    const int bk = blockIdx.x;
    const int d  = threadIdx.x;
    float h = 0.0f;
#pragma unroll 14
    for (int c = 0; c < NCH; ++c) {
        const size_t o = ((size_t)bk * NCH + c) * 128 + d;
        H0[o] = h;
        h = fmaf(Pa[o], h, Hl[o]);
    }
}

// ---------------- Scan pass 3a: dirs 0+1 interleaved, plain store ----------------
__global__ __launch_bounds__(128) void k_scan3a(const float* __restrict__ xc,
                                                const float* __restrict__ xdn,
                                                const float* __restrict__ dtw_g,
                                                const float* __restrict__ dtb_g,
                                                const float* __restrict__ alog,
                                                const float* __restrict__ ds_g,
                                                const float* __restrict__ H0,
                                                float* __restrict__ ysum)
{
    __shared__ float xds[CS * 16];
    const int b = blockIdx.x / NCH;
    const int c = blockIdx.x % NCH;
    const int d = threadIdx.x;
    const int c2 = NCH - 1 - c;
    const int bk0 = b * 4 + 0, bk1 = b * 4 + 1;
    const int l0a = c * CS;

    const float* xcb  = &xc[(size_t)b * LL * 128];
    const float* base = &xdn[(size_t)b * LL * 32];
    float* yb = &ysum[(size_t)b * LL * 128];

    {
        const int row = d >> 2;
        const int q   = (d & 3) * 4;
        *(float4*)&xds[row * 16 + q] = *(const float4*)&base[(size_t)(l0a + row) * 32 + q];
    }
    __syncthreads();

    float xv[CS];
#pragma unroll
    for (int i = 0; i < CS; ++i) xv[i] = xcb[(size_t)(l0a + i) * 128 + d];

    const float A0 = dtw_g[(0 * 128 + d) * 4 + 0];
    const float A1 = dtw_g[(0 * 128 + d) * 4 + 1];
    const float A2 = dtw_g[(0 * 128 + d) * 4 + 2];
    const float A3 = dtw_g[(0 * 128 + d) * 4 + 3];
    const float Ab = dtb_g[0 * 128 + d];
    const float An = -__expf(alog[0 * 128 + d]);
    const float AD = ds_g[0 * 128 + d];
    const float B0 = dtw_g[(1 * 128 + d) * 4 + 0];
    const float B1 = dtw_g[(1 * 128 + d) * 4 + 1];
    const float B2 = dtw_g[(1 * 128 + d) * 4 + 2];
    const float B3 = dtw_g[(1 * 128 + d) * 4 + 3];
    const float Bb = dtb_g[1 * 128 + d];
    const float Bn = -__expf(alog[1 * 128 + d]);
    const float BD = ds_g[1 * 128 + d];

    float y[CS];
#pragma unroll
    for (int i = 0; i < CS; ++i) y[i] = 0.0f;

    float hA = H0[((size_t)bk0 * NCH + c)  * 128 + d];
    float hB = H0[((size_t)bk1 * NCH + c2) * 128 + d];
#pragma unroll
    for (int i = 0; i < CS; ++i) {
        const int j = CS - 1 - i;
        const float* rA = &xds[i * 16];
        const float* rB = &xds[j * 16 + 8];
        const float drawA = fmaf(rA[0], A0, fmaf(rA[1], A1, fmaf(rA[2], A2, fmaf(rA[3], A3, Ab))));
        const float drawB = fmaf(rB[0], B0, fmaf(rB[1], B1, fmaf(rB[2], B2, fmaf(rB[3], B3, Bb))));
        const float dtA = softplus_(drawA);
        const float dtB = softplus_(drawB);
        const float dAA = __expf(dtA * An);
        const float dAB = __expf(dtB * Bn);
        hA = fmaf(dAA, hA, dtA * rA[4] * xv[i]);
        hB = fmaf(dAB, hB, dtB * rB[4] * xv[j]);
        y[i] += fmaf(hA, rA[5], AD * xv[i]);
        y[j] += fmaf(hB, rB[5], BD * xv[j]);
    }
#pragma unroll
    for (int i = 0; i < CS; ++i)
        yb[(size_t)(l0a + i) * 128 + d] = y[i];
}

// ---------------- Scan pass 3b + final: dirs 2+3, read 3a's ysum, LN+gate+mean ----------------
__global__ __launch_bounds__(128) void k_scan3bf(const float* __restrict__ xc,
                                                 const float* __restrict__ xdn,
                                                 const float* __restrict__ dtw_g,
                                                 const float* __restrict__ dtb_g,
                                                 const float* __restrict__ alog,
                                                 const float* __restrict__ ds_g,
                                                 const float* __restrict__ H0,
                                                 const float* __restrict__ ysum,
                                                 const float* __restrict__ zs,
                                                 const float* __restrict__ onw,
                                                 const float* __restrict__ onb,
                                                 float* __restrict__ out)
{
    __shared__ float xds[CS * 16];
    __shared__ float redS[2];
    __shared__ float redQ[2];
    const int b = blockIdx.x / NCH;
    const int c = blockIdx.x % NCH;
    const int d = threadIdx.x;
    const int wv = d >> 6;
    const int c2 = NCH - 1 - c;
    const int bk2 = b * 4 + 2, bk3 = b * 4 + 3;
    const int l0a = c * CS;

    const float* xcb  = &xc[(size_t)b * LL * 128];
    const float* base = &xdn[(size_t)b * LL * 32];
    const float* yb   = &ysum[(size_t)b * LL * 128];
    const float* zb   = &zs[(size_t)b * LL * 128];

    {
        const int row = d >> 2;
        const int q   = (d & 3) * 4;
        const int l   = l0a + row;
        const int prow = (l % HHH) * WWW + (l / HHH);
        *(float4*)&xds[row * 16 + q] = *(const float4*)&base[(size_t)prow * 32 + 16 + q];
    }
    __syncthreads();

    int pj[CS];
#pragma unroll
    for (int i = 0; i < CS; ++i) {
        const int l = l0a + i;
        pj[i] = (l % HHH) * WWW + (l / HHH);
    }
    float xv[CS];
#pragma unroll
    for (int i = 0; i < CS; ++i) xv[i] = xcb[(size_t)pj[i] * 128 + d];

    const float A0 = dtw_g[(2 * 128 + d) * 4 + 0];
    const float A1 = dtw_g[(2 * 128 + d) * 4 + 1];
    const float A2 = dtw_g[(2 * 128 + d) * 4 + 2];
    const float A3 = dtw_g[(2 * 128 + d) * 4 + 3];
    const float Ab = dtb_g[2 * 128 + d];
    const float An = -__expf(alog[2 * 128 + d]);
    const float AD = ds_g[2 * 128 + d];
    const float B0 = dtw_g[(3 * 128 + d) * 4 + 0];
    const float B1 = dtw_g[(3 * 128 + d) * 4 + 1];
    const float B2 = dtw_g[(3 * 128 + d) * 4 + 2];
    const float B3 = dtw_g[(3 * 128 + d) * 4 + 3];
    const float Bb = dtb_g[3 * 128 + d];
    const float Bn = -__expf(alog[3 * 128 + d]);
    const float BD = ds_g[3 * 128 + d];

    float y[CS];
#pragma unroll
    for (int i = 0; i < CS; ++i) y[i] = 0.0f;

    float hA = H0[((size_t)bk2 * NCH + c)  * 128 + d];
    float hB = H0[((size_t)bk3 * NCH + c2) * 128 + d];
#pragma unroll
    for (int i = 0; i < CS; ++i) {
        const int j = CS - 1 - i;
        const float* rA = &xds[i * 16];
        const float* rB = &xds[j * 16 + 8];
        const float drawA = fmaf(rA[0], A0, fmaf(rA[1], A1, fmaf(rA[2], A2, fmaf(rA[3], A3, Ab))));
        const float drawB = fmaf(rB[0], B0, fmaf(rB[1], B1, fmaf(rB[2], B2, fmaf(rB[3], B3, Bb))));
        const float dtA = softplus_(drawA);
        const float dtB = softplus_(drawB);
        const float dAA = __expf(dtA * An);
        const float dAB = __expf(dtB * Bn);
        hA = fmaf(dAA, hA, dtA * rA[4] * xv[i]);
        hB = fmaf(dAB, hB, dtB * rB[4] * xv[j]);
        y[i] += fmaf(hA, rA[5], AD * xv[i]);
        y[j] += fmaf(hB, rB[5], BD * xv[j]);
    }

    // add k0+k1 contribution (scan3a's store): complete 4-direction sum
#pragma unroll
    for (int i = 0; i < CS; ++i)
        y[i] += yb[(size_t)pj[i] * 128 + d];

    // LayerNorm over d (128 = 2 waves) + silu(z) gate + spatial-mean accumulate
    const float wd = onw[d];
    const float bd = onb[d];
    float acc = 0.0f;
    for (int i = 0; i < CS; ++i) {
        const float yt = y[i];
        float s = yt;
#pragma unroll
        for (int off = 32; off >= 1; off >>= 1) s += __shfl_xor(s, off, 64);
        if ((d & 63) == 0) redS[wv] = s;
        __syncthreads();
        const float mu = (redS[0] + redS[1]) * (1.0f / 128.0f);
        const float dv = yt - mu;
        float q = dv * dv;
#pragma unroll
        for (int off = 32; off >= 1; off >>= 1) q += __shfl_xor(q, off, 64);
        if ((d & 63) == 0) redQ[wv] = q;
        __syncthreads();
        const float var  = (redQ[0] + redQ[1]) * (1.0f / 128.0f);
        const float rstd = rsqrtf(var + 1e-5f);
        const float yn   = fmaf(dv * rstd, wd, bd);
        acc = fmaf(yn, zb[(size_t)pj[i] * 128 + d], acc);
    }
    atomicAdd(&out[b * 128 + d], acc * (1.0f / (float)LL));
}

extern "C" void kernel_launch(void* const* d_in, const int* in_sizes, int n_in,
                              void* d_out, int out_size, void* d_ws, size_t ws_size,
                              hipStream_t stream)
{
    const float* x     = (const float*)d_in[0];
    const float* ipw   = (const float*)d_in[1];
    const float* cw    = (const float*)d_in[2];
    const float* cb    = (const float*)d_in[3];
    const float* xpw   = (const float*)d_in[4];
    const float* dtw   = (const float*)d_in[5];
    const float* dtb   = (const float*)d_in[6];
    const float* alog  = (const float*)d_in[7];
    const float* dsg   = (const float*)d_in[8];
    const float* onw   = (const float*)d_in[9];
    const float* onb   = (const float*)d_in[10];
    float* out = (float*)d_out;

    float* ws   = (float*)d_ws;
    float* xi   = ws + OFF_XI;     // becomes ysum
    float* zs   = ws + OFF_ZS;
    float* xc   = ws + OFF_XC;
    float* xdn  = ws + OFF_XDN;
    float* Pa   = ws + OFF_PA;
    float* Hl   = ws + OFF_HL;
    float* H0   = ws + OFF_H0;
    float* cwT  = ws + OFF_CWT;
    float* ysum = xi;
    short* Whi = (short*)(ws + OFF_XC);
    short* Wlo = (short*)(ws + OFF_XC + 16384);

    hipMemsetAsync(out, 0, (size_t)out_size * 4, stream);

    k_wsplit<<<128, 256, 0, stream>>>(ipw, cw, Whi, Wlo, cwT);
    k_inproj<<<784, 256, 0, stream>>>(x, Whi, Wlo, xi, zs);

    k_conv4<<<1568, 256, 0, stream>>>(xi, cwT, cb, xc);

    k_projN<<<BB * 49, 256, 0, stream>>>(xc, xpw, xdn);

    k_scan1m<<<2 * BB * NCH, 128, 0, stream>>>(xc, xdn, dtw, dtb, alog, Pa, Hl);
    k_scan2<<<BB * KK, 128, 0, stream>>>(Pa, Hl, H0);
    k_scan3a<<<BB * NCH, 128, 0, stream>>>(xc, xdn, dtw, dtb, alog, dsg, H0, ysum);
    k_scan3bf<<<BB * NCH, 128, 0, stream>>>(xc, xdn, dtw, dtb, alog, dsg, H0, ysum,
                                            zs, onw, onb, out);
}

// Round 9
// 241.435 us; speedup vs baseline: 1.3369x; 1.3369x over previous
//
#include <hip/hip_runtime.h>
#include <math.h>

#define BB   16
#define HHH  56
#define WWW  56
#define LL   3136      // 56*56
#define DI_  128
#define KK   4
#define NCH  98        // chunks per (b,k)
#define CS   32        // chunk size; NCH*CS == LL

// workspace layout (floats)
#define OFF_XI   ((size_t)0)           // B*L*DI ; reused as YSUM
#define OFF_ZS   ((size_t)6422528)
#define OFF_XC   ((size_t)12845056)    // xc; also hosts Whi/Wlo BEFORE k_conv writes it
#define OFF_XDN  ((size_t)19267584)    // B*L*32
#define OFF_PA   ((size_t)20873216)
#define OFF_HL   ((size_t)21676032)
#define OFF_H0   ((size_t)22478848)
#define OFF_CWT  ((size_t)23281664)    // 9*128 transposed conv weights

typedef short s16x8 __attribute__((ext_vector_type(8)));
typedef float f32x4 __attribute__((ext_vector_type(4)));

__device__ __forceinline__ float sigmoidf_(float x) { return 1.0f / (1.0f + __expf(-x)); }
__device__ __forceinline__ float softplus_(float x) {
    return fmaxf(x, 0.0f) + __logf(1.0f + __expf(-fabsf(x)));
}

// split f into bf16 hi/lo (RNE)
__device__ __forceinline__ void bf16split(float f, short* hi, short* lo) {
    unsigned u = __float_as_uint(f);
    unsigned r = u + 0x7FFFu + ((u >> 16) & 1u);
    *hi = (short)(r >> 16);
    float hf = __uint_as_float(r & 0xFFFF0000u);
    float l  = f - hf;
    unsigned u2 = __float_as_uint(l);
    unsigned r2 = u2 + 0x7FFFu + ((u2 >> 16) & 1u);
    *lo = (short)(r2 >> 16);
}

// ---------------- Kernel W: pre-split in_proj weights + transpose conv weights ----------------
__global__ __launch_bounds__(256) void k_wsplit(const float* __restrict__ Wp,
                                                const float* __restrict__ cw,
                                                short* __restrict__ Whi,
                                                short* __restrict__ Wlo,
                                                float* __restrict__ cwT)
{
    const int idx = blockIdx.x * 256 + threadIdx.x;
    if (idx < 256 * 128) {
        short h, l;
        bf16split(Wp[idx], &h, &l);
        Whi[idx] = h;
        Wlo[idx] = l;
    }
    if (idx < 9 * 128) {
        const int t = idx >> 7;
        const int d = idx & 127;
        cwT[t * 128 + d] = cw[d * 9 + t];
    }
}

// ---------------- Kernel A: in_proj GEMM via bf16x3 MFMA ----------------
#define APAD 136   // 128 + 8 shorts row pad
__global__ __launch_bounds__(256) void k_inproj(const float* __restrict__ x,
                                                const short* __restrict__ Whi,
                                                const short* __restrict__ Wlo,
                                                float* __restrict__ xi,
                                                float* __restrict__ zs)
{
    __shared__ short Ahi[64 * APAD];
    __shared__ short Alo[64 * APAD];
    const int tid  = threadIdx.x;
    const int row0 = blockIdx.x * 64;

#pragma unroll
    for (int i = 0; i < 8; ++i) {
        const int idx4 = i * 256 + tid;
        const int row  = idx4 >> 5;
        const int k4   = (idx4 & 31) * 4;
        float4 v = *(const float4*)&x[(size_t)(row0 + row) * 128 + k4];
        const float f[4] = {v.x, v.y, v.z, v.w};
#pragma unroll
        for (int j = 0; j < 4; ++j) {
            short h, l;
            bf16split(f[j], &h, &l);
            Ahi[row * APAD + k4 + j] = h;
            Alo[row * APAD + k4 + j] = l;
        }
    }
    __syncthreads();

    const int w    = tid >> 6;
    const int lane = tid & 63;
    const int lr   = lane & 15;
    const int lk   = (lane >> 4) * 8;

    for (int cg = 0; cg < 4; ++cg) {
        const int col0 = cg * 64 + w * 16;
        s16x8 bhi[4], blo[4];
#pragma unroll
        for (int ks = 0; ks < 4; ++ks) {
            const size_t wo = (size_t)(col0 + lr) * 128 + ks * 32 + lk;
            bhi[ks] = *(const s16x8*)&Whi[wo];
            blo[ks] = *(const s16x8*)&Wlo[wo];
        }
#pragma unroll
        for (int rt = 0; rt < 4; ++rt) {
            f32x4 acc = {0.f, 0.f, 0.f, 0.f};
#pragma unroll
            for (int ks = 0; ks < 4; ++ks) {
                const int ao = (rt * 16 + lr) * APAD + ks * 32 + lk;
                s16x8 ahi = *(const s16x8*)&Ahi[ao];
                s16x8 alo = *(const s16x8*)&Alo[ao];
                acc = __builtin_amdgcn_mfma_f32_16x16x32_bf16(alo, bhi[ks], acc, 0, 0, 0);
                acc = __builtin_amdgcn_mfma_f32_16x16x32_bf16(ahi, blo[ks], acc, 0, 0, 0);
                acc = __builtin_amdgcn_mfma_f32_16x16x32_bf16(ahi, bhi[ks], acc, 0, 0, 0);
            }
            const int col = col0 + lr;
#pragma unroll
            for (int j = 0; j < 4; ++j) {
                const size_t row = row0 + rt * 16 + (lane >> 4) * 4 + j;
                const float v = acc[j];
                if (col < 128) {
                    xi[row * 128 + col] = v;
                } else {
                    zs[row * 128 + (col - 128)] = v * sigmoidf_(v);
                }
            }
        }
    }
}

// ---------------- Kernel B: depthwise conv, float4 x 4 rows, XCD-swizzled ----------------
__global__ __launch_bounds__(256) void k_conv4(const float* __restrict__ xi,
                                               const float* __restrict__ cwT,
                                               const float* __restrict__ cb,
                                               float* __restrict__ xc)
{
    const int wid = (blockIdx.x & 7) * 196 + (blockIdx.x >> 3);   // 1568 = 8*196
    const int idx = wid * 256 + threadIdx.x;
    const int d0  = (idx & 31) * 4;
    int rest = idx >> 5;
    const int w  = rest % WWW;
    rest /= WWW;
    const int hq = rest % 14;
    const int b  = rest / 14;
    const int h0 = hq * 4;

    float4 wt[9];
#pragma unroll
    for (int t = 0; t < 9; ++t) wt[t] = *(const float4*)&cwT[t * 128 + d0];
    const float4 bias = *(const float4*)&cb[d0];

    float4 a0 = bias, a1 = bias, a2 = bias, a3 = bias;
    const float* base = &xi[(size_t)b * LL * 128 + d0];
#pragma unroll
    for (int dr = -1; dr <= 4; ++dr) {
        const int hh = h0 + dr;
        if (hh < 0 || hh >= HHH) continue;
#pragma unroll
        for (int dc = -1; dc <= 1; ++dc) {
            const int ww = w + dc;
            if (ww < 0 || ww >= WWW) continue;
            const float4 v = *(const float4*)&base[(size_t)(hh * WWW + ww) * 128];
#pragma unroll
            for (int r = 0; r < 4; ++r) {
                const int tap = dr - r;
                if (tap < -1 || tap > 1) continue;
                const float4 wv = wt[(tap + 1) * 3 + (dc + 1)];
                float4* a = (r == 0) ? &a0 : (r == 1) ? &a1 : (r == 2) ? &a2 : &a3;
                a->x = fmaf(v.x, wv.x, a->x);
                a->y = fmaf(v.y, wv.y, a->y);
                a->z = fmaf(v.z, wv.z, a->z);
                a->w = fmaf(v.w, wv.w, a->w);
            }
        }
    }
    float4 av[4] = {a0, a1, a2, a3};
#pragma unroll
    for (int r = 0; r < 4; ++r) {
        float4 o;
        o.x = av[r].x * sigmoidf_(av[r].x);
        o.y = av[r].y * sigmoidf_(av[r].y);
        o.z = av[r].z * sigmoidf_(av[r].z);
        o.w = av[r].w * sigmoidf_(av[r].w);
        *(float4*)&xc[((size_t)b * LL + (h0 + r) * WWW + w) * 128 + d0] = o;
    }
}

// ---------------- Kernel C: projection in natural order ----------------
__global__ __launch_bounds__(256) void k_projN(const float* __restrict__ xc,
                                               const float* __restrict__ xpw,
                                               float* __restrict__ xdn)
{
    __shared__ float xs[64 * 129];
    __shared__ float wl[24 * 128];
    const int tid = threadIdx.x;
    const int b   = blockIdx.x / 49;
    const int p0  = (blockIdx.x % 49) * 64;

    for (int i = tid; i < 24 * 128; i += 256) wl[i] = xpw[i];

#pragma unroll
    for (int i = 0; i < 8; ++i) {
        const int idx4 = i * 256 + tid;
        const int row  = idx4 >> 5;
        const int d4   = (idx4 & 31) * 4;
        float4 v = *(const float4*)&xc[((size_t)b * LL + p0 + row) * 128 + d4];
        xs[row * 129 + d4 + 0] = v.x;
        xs[row * 129 + d4 + 1] = v.y;
        xs[row * 129 + d4 + 2] = v.z;
        xs[row * 129 + d4 + 3] = v.w;
    }
    __syncthreads();

    const int ks   = tid >> 6;
    const int lane = tid & 63;
    float a0 = 0.f, a1 = 0.f, a2 = 0.f, a3 = 0.f, a4 = 0.f, a5 = 0.f;
    const float* wb = &wl[ks * 6 * 128];
#pragma unroll 4
    for (int d = 0; d < 128; ++d) {
        const float xv = xs[lane * 129 + d];
        a0 = fmaf(xv, wb[0 * 128 + d], a0);
        a1 = fmaf(xv, wb[1 * 128 + d], a1);
        a2 = fmaf(xv, wb[2 * 128 + d], a2);
        a3 = fmaf(xv, wb[3 * 128 + d], a3);
        a4 = fmaf(xv, wb[4 * 128 + d], a4);
        a5 = fmaf(xv, wb[5 * 128 + d], a5);
    }
    float* o = &xdn[((size_t)(b * LL + p0 + lane)) * 32 + ks * 8];
    o[0] = a0; o[1] = a1; o[2] = a2; o[3] = a3; o[4] = a4; o[5] = a5;
}

// ---------------- Scan pass 1: merged direction pairs, interleaved chains ----------------
__global__ __launch_bounds__(128) void k_scan1m(const float* __restrict__ xc,
                                                const float* __restrict__ xdn,
                                                const float* __restrict__ dtw_g,
                                                const float* __restrict__ dtb_g,
                                                const float* __restrict__ alog,
                                                float* __restrict__ Pa,
                                                float* __restrict__ Hl)
{
    __shared__ float xds[CS * 16];
    const int mode = blockIdx.x / (BB * NCH);
    const int rem  = blockIdx.x % (BB * NCH);
    const int b = rem / NCH;
    const int c = rem % NCH;
    const int d = threadIdx.x;
    const int c2 = NCH - 1 - c;
    const int l0a = c * CS;
    const int kA = mode * 2;
    const int kB = kA + 1;
    const int bkA = b * 4 + kA, bkB = b * 4 + kB;

    const float* xcb  = &xc[(size_t)b * LL * 128];
    const float* base = &xdn[(size_t)b * LL * 32];

    {
        const int row = d >> 2;
        const int q   = (d & 3) * 4;
        int prow;
        if (mode == 0) prow = l0a + row;
        else { const int l = l0a + row; prow = (l % HHH) * WWW + (l / HHH); }
        *(float4*)&xds[row * 16 + q] = *(const float4*)&base[(size_t)prow * 32 + mode * 16 + q];
    }
    __syncthreads();

    int pj[CS];
    if (mode == 0) {
#pragma unroll
        for (int i = 0; i < CS; ++i) pj[i] = l0a + i;
    } else {
#pragma unroll
        for (int i = 0; i < CS; ++i) {
            const int l = l0a + i;
            pj[i] = (l % HHH) * WWW + (l / HHH);
        }
    }
    float xv[CS];
#pragma unroll
    for (int i = 0; i < CS; ++i) xv[i] = xcb[(size_t)pj[i] * 128 + d];

    const float A0 = dtw_g[(kA * 128 + d) * 4 + 0];
    const float A1 = dtw_g[(kA * 128 + d) * 4 + 1];
    const float A2 = dtw_g[(kA * 128 + d) * 4 + 2];
    const float A3 = dtw_g[(kA * 128 + d) * 4 + 3];
    const float Ab = dtb_g[kA * 128 + d];
    const float An = -__expf(alog[kA * 128 + d]);
    const float B0 = dtw_g[(kB * 128 + d) * 4 + 0];
    const float B1 = dtw_g[(kB * 128 + d) * 4 + 1];
    const float B2 = dtw_g[(kB * 128 + d) * 4 + 2];
    const float B3 = dtw_g[(kB * 128 + d) * 4 + 3];
    const float Bb = dtb_g[kB * 128 + d];
    const float Bn = -__expf(alog[kB * 128 + d]);

    float PA = 1.0f, hA = 0.0f, PB = 1.0f, hB = 0.0f;
#pragma unroll
    for (int i = 0; i < CS; ++i) {
        const int j = CS - 1 - i;
        const float* rA = &xds[i * 16];
        const float* rB = &xds[j * 16 + 8];
        const float drawA = fmaf(rA[0], A0, fmaf(rA[1], A1, fmaf(rA[2], A2, fmaf(rA[3], A3, Ab))));
        const float drawB = fmaf(rB[0], B0, fmaf(rB[1], B1, fmaf(rB[2], B2, fmaf(rB[3], B3, Bb))));
        const float dtA = softplus_(drawA);
        const float dtB = softplus_(drawB);
        const float dAA = __expf(dtA * An);
        const float dAB = __expf(dtB * Bn);
        PA *= dAA;
        PB *= dAB;
        hA = fmaf(dAA, hA, dtA * rA[4] * xv[i]);
        hB = fmaf(dAB, hB, dtB * rB[4] * xv[j]);
    }
    Pa[((size_t)bkA * NCH + c)  * 128 + d] = PA;
    Hl[((size_t)bkA * NCH + c)  * 128 + d] = hA;
    Pa[((size_t)bkB * NCH + c2) * 128 + d] = PB;
    Hl[((size_t)bkB * NCH + c2) * 128 + d] = hB;
}

// ---------------- Scan pass 2: combine chunk summaries ----------------
__global__ __launch_bounds__(128) void k_scan2(const float* __restrict__ Pa,
                                               const float* __restrict__ Hl,
                                               float* __restrict__ H0)
{
    const int bk = blockIdx.x;
    const int d  = threadIdx.x;
    float h = 0.0f;
#pragma unroll 14
    for (int c = 0; c < NCH; ++c) {
        const size_t o = ((size_t)bk * NCH + c) * 128 + d;
        H0[o] = h;
        h = fmaf(Pa[o], h, Hl[o]);
    }
}

// ---------------- Scan pass 3a: dirs 0+1 interleaved, plain store ----------------
__global__ __launch_bounds__(128) void k_scan3a(const float* __restrict__ xc,
                                                const float* __restrict__ xdn,
                                                const float* __restrict__ dtw_g,
                                                const float* __restrict__ dtb_g,
                                                const float* __restrict__ alog,
                                                const float* __restrict__ ds_g,
                                                const float* __restrict__ H0,
                                                float* __restrict__ ysum)
{
    __shared__ float xds[CS * 16];
    const int b = blockIdx.x / NCH;
    const int c = blockIdx.x % NCH;
    const int d = threadIdx.x;
    const int c2 = NCH - 1 - c;
    const int bk0 = b * 4 + 0, bk1 = b * 4 + 1;
    const int l0a = c * CS;

    const float* xcb  = &xc[(size_t)b * LL * 128];
    const float* base = &xdn[(size_t)b * LL * 32];
    float* yb = &ysum[(size_t)b * LL * 128];

    {
        const int row = d >> 2;
        const int q   = (d & 3) * 4;
        *(float4*)&xds[row * 16 + q] = *(const float4*)&base[(size_t)(l0a + row) * 32 + q];
    }
    __syncthreads();

    float xv[CS];
#pragma unroll
    for (int i = 0; i < CS; ++i) xv[i] = xcb[(size_t)(l0a + i) * 128 + d];

    const float A0 = dtw_g[(0 * 128 + d) * 4 + 0];
    const float A1 = dtw_g[(0 * 128 + d) * 4 + 1];
    const float A2 = dtw_g[(0 * 128 + d) * 4 + 2];
    const float A3 = dtw_g[(0 * 128 + d) * 4 + 3];
    const float Ab = dtb_g[0 * 128 + d];
    const float An = -__expf(alog[0 * 128 + d]);
    const float AD = ds_g[0 * 128 + d];
    const float B0 = dtw_g[(1 * 128 + d) * 4 + 0];
    const float B1 = dtw_g[(1 * 128 + d) * 4 + 1];
    const float B2 = dtw_g[(1 * 128 + d) * 4 + 2];
    const float B3 = dtw_g[(1 * 128 + d) * 4 + 3];
    const float Bb = dtb_g[1 * 128 + d];
    const float Bn = -__expf(alog[1 * 128 + d]);
    const float BD = ds_g[1 * 128 + d];

    float y[CS];
#pragma unroll
    for (int i = 0; i < CS; ++i) y[i] = 0.0f;

    float hA = H0[((size_t)bk0 * NCH + c)  * 128 + d];
    float hB = H0[((size_t)bk1 * NCH + c2) * 128 + d];
#pragma unroll
    for (int i = 0; i < CS; ++i) {
        const int j = CS - 1 - i;
        const float* rA = &xds[i * 16];
        const float* rB = &xds[j * 16 + 8];
        const float drawA = fmaf(rA[0], A0, fmaf(rA[1], A1, fmaf(rA[2], A2, fmaf(rA[3], A3, Ab))));
        const float drawB = fmaf(rB[0], B0, fmaf(rB[1], B1, fmaf(rB[2], B2, fmaf(rB[3], B3, Bb))));
        const float dtA = softplus_(drawA);
        const float dtB = softplus_(drawB);
        const float dAA = __expf(dtA * An);
        const float dAB = __expf(dtB * Bn);
        hA = fmaf(dAA, hA, dtA * rA[4] * xv[i]);
        hB = fmaf(dAB, hB, dtB * rB[4] * xv[j]);
        y[i] += fmaf(hA, rA[5], AD * xv[i]);
        y[j] += fmaf(hB, rB[5], BD * xv[j]);
    }
#pragma unroll
    for (int i = 0; i < CS; ++i)
        yb[(size_t)(l0a + i) * 128 + d] = y[i];
}

// ---------------- Scan pass 3b + final: dirs 2+3, read 3a's ysum, LN+gate+mean ----------------
// LN via 3-barrier LDS scheme: spill y, 4-lane-per-position parallel reduce, normalize from regs
#define YPAD 132
__global__ __launch_bounds__(128) void k_scan3bf(const float* __restrict__ xc,
                                                 const float* __restrict__ xdn,
                                                 const float* __restrict__ dtw_g,
                                                 const float* __restrict__ dtb_g,
                                                 const float* __restrict__ alog,
                                                 const float* __restrict__ ds_g,
                                                 const float* __restrict__ H0,
                                                 const float* __restrict__ ysum,
                                                 const float* __restrict__ zs,
                                                 const float* __restrict__ onw,
                                                 const float* __restrict__ onb,
                                                 float* __restrict__ out)
{
    __shared__ float xds[CS * 16];
    __shared__ float yl[CS * YPAD];
    __shared__ float muS[CS];
    __shared__ float rsS[CS];
    const int b = blockIdx.x / NCH;
    const int c = blockIdx.x % NCH;
    const int d = threadIdx.x;
    const int c2 = NCH - 1 - c;
    const int bk2 = b * 4 + 2, bk3 = b * 4 + 3;
    const int l0a = c * CS;

    const float* xcb  = &xc[(size_t)b * LL * 128];
    const float* base = &xdn[(size_t)b * LL * 32];
    const float* yb   = &ysum[(size_t)b * LL * 128];
    const float* zb   = &zs[(size_t)b * LL * 128];

    {
        const int row = d >> 2;
        const int q   = (d & 3) * 4;
        const int l   = l0a + row;
        const int prow = (l % HHH) * WWW + (l / HHH);
        *(float4*)&xds[row * 16 + q] = *(const float4*)&base[(size_t)prow * 32 + 16 + q];
    }
    __syncthreads();

    int pj[CS];
#pragma unroll
    for (int i = 0; i < CS; ++i) {
        const int l = l0a + i;
        pj[i] = (l % HHH) * WWW + (l / HHH);
    }
    float xv[CS];
#pragma unroll
    for (int i = 0; i < CS; ++i) xv[i] = xcb[(size_t)pj[i] * 128 + d];

    const float A0 = dtw_g[(2 * 128 + d) * 4 + 0];
    const float A1 = dtw_g[(2 * 128 + d) * 4 + 1];
    const float A2 = dtw_g[(2 * 128 + d) * 4 + 2];
    const float A3 = dtw_g[(2 * 128 + d) * 4 + 3];
    const float Ab = dtb_g[2 * 128 + d];
    const float An = -__expf(alog[2 * 128 + d]);
    const float AD = ds_g[2 * 128 + d];
    const float B0 = dtw_g[(3 * 128 + d) * 4 + 0];
    const float B1 = dtw_g[(3 * 128 + d) * 4 + 1];
    const float B2 = dtw_g[(3 * 128 + d) * 4 + 2];
    const float B3 = dtw_g[(3 * 128 + d) * 4 + 3];
    const float Bb = dtb_g[3 * 128 + d];
    const float Bn = -__expf(alog[3 * 128 + d]);
    const float BD = ds_g[3 * 128 + d];

    float y[CS];
#pragma unroll
    for (int i = 0; i < CS; ++i) y[i] = 0.0f;

    float hA = H0[((size_t)bk2 * NCH + c)  * 128 + d];
    float hB = H0[((size_t)bk3 * NCH + c2) * 128 + d];
#pragma unroll
    for (int i = 0; i < CS; ++i) {
        const int j = CS - 1 - i;
        const float* rA = &xds[i * 16];
        const float* rB = &xds[j * 16 + 8];
        const float drawA = fmaf(rA[0], A0, fmaf(rA[1], A1, fmaf(rA[2], A2, fmaf(rA[3], A3, Ab))));
        const float drawB = fmaf(rB[0], B0, fmaf(rB[1], B1, fmaf(rB[2], B2, fmaf(rB[3], B3, Bb))));
        const float dtA = softplus_(drawA);
        const float dtB = softplus_(drawB);
        const float dAA = __expf(dtA * An);
        const float dAB = __expf(dtB * Bn);
        hA = fmaf(dAA, hA, dtA * rA[4] * xv[i]);
        hB = fmaf(dAB, hB, dtB * rB[4] * xv[j]);
        y[i] += fmaf(hA, rA[5], AD * xv[i]);
        y[j] += fmaf(hB, rB[5], BD * xv[j]);
    }

    // add k0+k1 contribution (scan3a's store): complete 4-direction sum; spill to LDS
#pragma unroll
    for (int i = 0; i < CS; ++i) {
        y[i] += yb[(size_t)pj[i] * 128 + d];
        yl[i * YPAD + d] = y[i];
    }
    __syncthreads();

    // parallel LN stats: 4 lanes per position
    {
        const int pos = d >> 2;
        const int q   = d & 3;
        const float* yrow = &yl[pos * YPAD + q * 32];
        float sm = 0.0f;
#pragma unroll
        for (int j = 0; j < 32; ++j) sm += yrow[j];
        sm += __shfl_xor(sm, 1, 64);
        sm += __shfl_xor(sm, 2, 64);
        const float mu = sm * (1.0f / 128.0f);
        float sq = 0.0f;
#pragma unroll
        for (int j = 0; j < 32; ++j) { const float t = yrow[j] - mu; sq = fmaf(t, t, sq); }
        sq += __shfl_xor(sq, 1, 64);
        sq += __shfl_xor(sq, 2, 64);
        if (q == 0) {
            muS[pos] = mu;
            rsS[pos] = rsqrtf(sq * (1.0f / 128.0f) + 1e-5f);
        }
    }
    __syncthreads();

    // normalize from registers, gate, accumulate spatial mean
    const float wd = onw[d];
    const float bd = onb[d];
    float acc = 0.0f;
#pragma unroll
    for (int i = 0; i < CS; ++i) {
        const float yn = fmaf((y[i] - muS[i]) * rsS[i], wd, bd);
        acc = fmaf(yn, zb[(size_t)pj[i] * 128 + d], acc);
    }
    atomicAdd(&out[b * 128 + d], acc * (1.0f / (float)LL));
}

extern "C" void kernel_launch(void* const* d_in, const int* in_sizes, int n_in,
                              void* d_out, int out_size, void* d_ws, size_t ws_size,
                              hipStream_t stream)
{
    const float* x     = (const float*)d_in[0];
    const float* ipw   = (const float*)d_in[1];
    const float* cw    = (const float*)d_in[2];
    const float* cb    = (const float*)d_in[3];
    const float* xpw   = (const float*)d_in[4];
    const float* dtw   = (const float*)d_in[5];
    const float* dtb   = (const float*)d_in[6];
    const float* alog  = (const float*)d_in[7];
    const float* dsg   = (const float*)d_in[8];
    const float* onw   = (const float*)d_in[9];
    const float* onb   = (const float*)d_in[10];
    float* out = (float*)d_out;

    float* ws   = (float*)d_ws;
    float* xi   = ws + OFF_XI;     // becomes ysum
    float* zs   = ws + OFF_ZS;
    float* xc   = ws + OFF_XC;
    float* xdn  = ws + OFF_XDN;
    float* Pa   = ws + OFF_PA;
    float* Hl   = ws + OFF_HL;
    float* H0   = ws + OFF_H0;
    float* cwT  = ws + OFF_CWT;
    float* ysum = xi;
    short* Whi = (short*)(ws + OFF_XC);
    short* Wlo = (short*)(ws + OFF_XC + 16384);

    hipMemsetAsync(out, 0, (size_t)out_size * 4, stream);

    k_wsplit<<<128, 256, 0, stream>>>(ipw, cw, Whi, Wlo, cwT);
    k_inproj<<<784, 256, 0, stream>>>(x, Whi, Wlo, xi, zs);

    k_conv4<<<1568, 256, 0, stream>>>(xi, cwT, cb, xc);

    k_projN<<<BB * 49, 256, 0, stream>>>(xc, xpw, xdn);

    k_scan1m<<<2 * BB * NCH, 128, 0, stream>>>(xc, xdn, dtw, dtb, alog, Pa, Hl);
    k_scan2<<<BB * KK, 128, 0, stream>>>(Pa, Hl, H0);
    k_scan3a<<<BB * NCH, 128, 0, stream>>>(xc, xdn, dtw, dtb, alog, dsg, H0, ysum);
    k_scan3bf<<<BB * NCH, 128, 0, stream>>>(xc, xdn, dtw, dtb, alog, dsg, H0, ysum,
                                            zs, onw, onb, out);
}

// Round 10
// 219.743 us; speedup vs baseline: 1.4689x; 1.0987x over previous
//
#include <hip/hip_runtime.h>
#include <math.h>

#define BB   16
#define HHH  56
#define WWW  56
#define LL   3136      // 56*56
#define DI_  128
#define KK   4
#define NCH  196       // chunks per (b,k)
#define CS   16        // chunk size; NCH*CS == LL

// workspace layout (floats)
#define OFF_XI   ((size_t)0)           // B*L*DI ; reused as YSUM
#define OFF_ZS   ((size_t)6422528)
#define OFF_XC   ((size_t)12845056)    // xc; also hosts Whi/Wlo BEFORE k_conv writes it
#define OFF_XDN  ((size_t)19267584)    // B*L*32
#define OFF_PA   ((size_t)20873216)    // B*K*NCH*128 = 1605632
#define OFF_HL   ((size_t)22478848)
#define OFF_H0   ((size_t)24084480)
#define OFF_CWT  ((size_t)25690112)    // 9*128 transposed conv weights

typedef short s16x8 __attribute__((ext_vector_type(8)));
typedef float f32x4 __attribute__((ext_vector_type(4)));

__device__ __forceinline__ float sigmoidf_(float x) { return 1.0f / (1.0f + __expf(-x)); }
__device__ __forceinline__ float softplus_(float x) {
    return fmaxf(x, 0.0f) + __logf(1.0f + __expf(-fabsf(x)));
}

// split f into bf16 hi/lo (RNE)
__device__ __forceinline__ void bf16split(float f, short* hi, short* lo) {
    unsigned u = __float_as_uint(f);
    unsigned r = u + 0x7FFFu + ((u >> 16) & 1u);
    *hi = (short)(r >> 16);
    float hf = __uint_as_float(r & 0xFFFF0000u);
    float l  = f - hf;
    unsigned u2 = __float_as_uint(l);
    unsigned r2 = u2 + 0x7FFFu + ((u2 >> 16) & 1u);
    *lo = (short)(r2 >> 16);
}

// ---------------- Kernel W: pre-split in_proj weights + transpose conv weights ----------------
__global__ __launch_bounds__(256) void k_wsplit(const float* __restrict__ Wp,
                                                const float* __restrict__ cw,
                                                short* __restrict__ Whi,
                                                short* __restrict__ Wlo,
                                                float* __restrict__ cwT)
{
    const int idx = blockIdx.x * 256 + threadIdx.x;
    if (idx < 256 * 128) {
        short h, l;
        bf16split(Wp[idx], &h, &l);
        Whi[idx] = h;
        Wlo[idx] = l;
    }
    if (idx < 9 * 128) {
        const int t = idx >> 7;
        const int d = idx & 127;
        cwT[t * 128 + d] = cw[d * 9 + t];
    }
}

// ---------------- Kernel A: in_proj GEMM via bf16x3 MFMA ----------------
#define APAD 136   // 128 + 8 shorts row pad
__global__ __launch_bounds__(256) void k_inproj(const float* __restrict__ x,
                                                const short* __restrict__ Whi,
                                                const short* __restrict__ Wlo,
                                                float* __restrict__ xi,
                                                float* __restrict__ zs)
{
    __shared__ short Ahi[64 * APAD];
    __shared__ short Alo[64 * APAD];
    const int tid  = threadIdx.x;
    const int row0 = blockIdx.x * 64;

#pragma unroll
    for (int i = 0; i < 8; ++i) {
        const int idx4 = i * 256 + tid;
        const int row  = idx4 >> 5;
        const int k4   = (idx4 & 31) * 4;
        float4 v = *(const float4*)&x[(size_t)(row0 + row) * 128 + k4];
        const float f[4] = {v.x, v.y, v.z, v.w};
#pragma unroll
        for (int j = 0; j < 4; ++j) {
            short h, l;
            bf16split(f[j], &h, &l);
            Ahi[row * APAD + k4 + j] = h;
            Alo[row * APAD + k4 + j] = l;
        }
    }
    __syncthreads();

    const int w    = tid >> 6;
    const int lane = tid & 63;
    const int lr   = lane & 15;
    const int lk   = (lane >> 4) * 8;

    for (int cg = 0; cg < 4; ++cg) {
        const int col0 = cg * 64 + w * 16;
        s16x8 bhi[4], blo[4];
#pragma unroll
        for (int ks = 0; ks < 4; ++ks) {
            const size_t wo = (size_t)(col0 + lr) * 128 + ks * 32 + lk;
            bhi[ks] = *(const s16x8*)&Whi[wo];
            blo[ks] = *(const s16x8*)&Wlo[wo];
        }
#pragma unroll
        for (int rt = 0; rt < 4; ++rt) {
            f32x4 acc = {0.f, 0.f, 0.f, 0.f};
#pragma unroll
            for (int ks = 0; ks < 4; ++ks) {
                const int ao = (rt * 16 + lr) * APAD + ks * 32 + lk;
                s16x8 ahi = *(const s16x8*)&Ahi[ao];
                s16x8 alo = *(const s16x8*)&Alo[ao];
                acc = __builtin_amdgcn_mfma_f32_16x16x32_bf16(alo, bhi[ks], acc, 0, 0, 0);
                acc = __builtin_amdgcn_mfma_f32_16x16x32_bf16(ahi, blo[ks], acc, 0, 0, 0);
                acc = __builtin_amdgcn_mfma_f32_16x16x32_bf16(ahi, bhi[ks], acc, 0, 0, 0);
            }
            const int col = col0 + lr;
#pragma unroll
            for (int j = 0; j < 4; ++j) {
                const size_t row = row0 + rt * 16 + (lane >> 4) * 4 + j;
                const float v = acc[j];
                if (col < 128) {
                    xi[row * 128 + col] = v;
                } else {
                    zs[row * 128 + (col - 128)] = v * sigmoidf_(v);
                }
            }
        }
    }
}

// ---------------- Kernel B: depthwise conv, float4 x 4 rows, XCD-swizzled ----------------
__global__ __launch_bounds__(256) void k_conv4(const float* __restrict__ xi,
                                               const float* __restrict__ cwT,
                                               const float* __restrict__ cb,
                                               float* __restrict__ xc)
{
    const int wid = (blockIdx.x & 7) * 196 + (blockIdx.x >> 3);   // 1568 = 8*196
    const int idx = wid * 256 + threadIdx.x;
    const int d0  = (idx & 31) * 4;
    int rest = idx >> 5;
    const int w  = rest % WWW;
    rest /= WWW;
    const int hq = rest % 14;
    const int b  = rest / 14;
    const int h0 = hq * 4;

    float4 wt[9];
#pragma unroll
    for (int t = 0; t < 9; ++t) wt[t] = *(const float4*)&cwT[t * 128 + d0];
    const float4 bias = *(const float4*)&cb[d0];

    float4 a0 = bias, a1 = bias, a2 = bias, a3 = bias;
    const float* base = &xi[(size_t)b * LL * 128 + d0];
#pragma unroll
    for (int dr = -1; dr <= 4; ++dr) {
        const int hh = h0 + dr;
        if (hh < 0 || hh >= HHH) continue;
#pragma unroll
        for (int dc = -1; dc <= 1; ++dc) {
            const int ww = w + dc;
            if (ww < 0 || ww >= WWW) continue;
            const float4 v = *(const float4*)&base[(size_t)(hh * WWW + ww) * 128];
#pragma unroll
            for (int r = 0; r < 4; ++r) {
                const int tap = dr - r;
                if (tap < -1 || tap > 1) continue;
                const float4 wv = wt[(tap + 1) * 3 + (dc + 1)];
                float4* a = (r == 0) ? &a0 : (r == 1) ? &a1 : (r == 2) ? &a2 : &a3;
                a->x = fmaf(v.x, wv.x, a->x);
                a->y = fmaf(v.y, wv.y, a->y);
                a->z = fmaf(v.z, wv.z, a->z);
                a->w = fmaf(v.w, wv.w, a->w);
            }
        }
    }
    float4 av[4] = {a0, a1, a2, a3};
#pragma unroll
    for (int r = 0; r < 4; ++r) {
        float4 o;
        o.x = av[r].x * sigmoidf_(av[r].x);
        o.y = av[r].y * sigmoidf_(av[r].y);
        o.z = av[r].z * sigmoidf_(av[r].z);
        o.w = av[r].w * sigmoidf_(av[r].w);
        *(float4*)&xc[((size_t)b * LL + (h0 + r) * WWW + w) * 128 + d0] = o;
    }
}

// ---------------- Kernel C: projection in natural order ----------------
__global__ __launch_bounds__(256) void k_projN(const float* __restrict__ xc,
                                               const float* __restrict__ xpw,
                                               float* __restrict__ xdn)
{
    __shared__ float xs[64 * 129];
    __shared__ float wl[24 * 128];
    const int tid = threadIdx.x;
    const int b   = blockIdx.x / 49;
    const int p0  = (blockIdx.x % 49) * 64;

    for (int i = tid; i < 24 * 128; i += 256) wl[i] = xpw[i];

#pragma unroll
    for (int i = 0; i < 8; ++i) {
        const int idx4 = i * 256 + tid;
        const int row  = idx4 >> 5;
        const int d4   = (idx4 & 31) * 4;
        float4 v = *(const float4*)&xc[((size_t)b * LL + p0 + row) * 128 + d4];
        xs[row * 129 + d4 + 0] = v.x;
        xs[row * 129 + d4 + 1] = v.y;
        xs[row * 129 + d4 + 2] = v.z;
        xs[row * 129 + d4 + 3] = v.w;
    }
    __syncthreads();

    const int ks   = tid >> 6;
    const int lane = tid & 63;
    float a0 = 0.f, a1 = 0.f, a2 = 0.f, a3 = 0.f, a4 = 0.f, a5 = 0.f;
    const float* wb = &wl[ks * 6 * 128];
#pragma unroll 4
    for (int d = 0; d < 128; ++d) {
        const float xv = xs[lane * 129 + d];
        a0 = fmaf(xv, wb[0 * 128 + d], a0);
        a1 = fmaf(xv, wb[1 * 128 + d], a1);
        a2 = fmaf(xv, wb[2 * 128 + d], a2);
        a3 = fmaf(xv, wb[3 * 128 + d], a3);
        a4 = fmaf(xv, wb[4 * 128 + d], a4);
        a5 = fmaf(xv, wb[5 * 128 + d], a5);
    }
    float* o = &xdn[((size_t)(b * LL + p0 + lane)) * 32 + ks * 8];
    o[0] = a0; o[1] = a1; o[2] = a2; o[3] = a3; o[4] = a4; o[5] = a5;
}

// ---------------- Scan pass 1: merged direction pairs, interleaved chains ----------------
// grid: 2*BB*NCH; mode 0 -> dirs {0,1}, mode 1 -> dirs {2,3}
__global__ __launch_bounds__(128) void k_scan1m(const float* __restrict__ xc,
                                                const float* __restrict__ xdn,
                                                const float* __restrict__ dtw_g,
                                                const float* __restrict__ dtb_g,
                                                const float* __restrict__ alog,
                                                float* __restrict__ Pa,
                                                float* __restrict__ Hl)
{
    __shared__ float xds[CS * 16];
    const int mode = blockIdx.x / (BB * NCH);
    const int rem  = blockIdx.x % (BB * NCH);
    const int b = rem / NCH;
    const int c = rem % NCH;
    const int d = threadIdx.x;
    const int c2 = NCH - 1 - c;
    const int l0a = c * CS;
    const int kA = mode * 2;
    const int kB = kA + 1;
    const int bkA = b * 4 + kA, bkB = b * 4 + kB;

    const float* xcb  = &xc[(size_t)b * LL * 128];
    const float* base = &xdn[(size_t)b * LL * 32];

    if (d < CS * 4) {   // 16 rows x 4 quads
        const int row = d >> 2;
        const int q   = (d & 3) * 4;
        int prow;
        if (mode == 0) prow = l0a + row;
        else { const int l = l0a + row; prow = (l % HHH) * WWW + (l / HHH); }
        *(float4*)&xds[row * 16 + q] = *(const float4*)&base[(size_t)prow * 32 + mode * 16 + q];
    }
    __syncthreads();

    int pj[CS];
    if (mode == 0) {
#pragma unroll
        for (int i = 0; i < CS; ++i) pj[i] = l0a + i;
    } else {
#pragma unroll
        for (int i = 0; i < CS; ++i) {
            const int l = l0a + i;
            pj[i] = (l % HHH) * WWW + (l / HHH);
        }
    }
    float xv[CS];
#pragma unroll
    for (int i = 0; i < CS; ++i) xv[i] = xcb[(size_t)pj[i] * 128 + d];

    const float A0 = dtw_g[(kA * 128 + d) * 4 + 0];
    const float A1 = dtw_g[(kA * 128 + d) * 4 + 1];
    const float A2 = dtw_g[(kA * 128 + d) * 4 + 2];
    const float A3 = dtw_g[(kA * 128 + d) * 4 + 3];
    const float Ab = dtb_g[kA * 128 + d];
    const float An = -__expf(alog[kA * 128 + d]);
    const float B0 = dtw_g[(kB * 128 + d) * 4 + 0];
    const float B1 = dtw_g[(kB * 128 + d) * 4 + 1];
    const float B2 = dtw_g[(kB * 128 + d) * 4 + 2];
    const float B3 = dtw_g[(kB * 128 + d) * 4 + 3];
    const float Bb = dtb_g[kB * 128 + d];
    const float Bn = -__expf(alog[kB * 128 + d]);

    float PA = 1.0f, hA = 0.0f, PB = 1.0f, hB = 0.0f;
#pragma unroll
    for (int i = 0; i < CS; ++i) {
        const int j = CS - 1 - i;
        const float* rA = &xds[i * 16];
        const float* rB = &xds[j * 16 + 8];
        const float drawA = fmaf(rA[0], A0, fmaf(rA[1], A1, fmaf(rA[2], A2, fmaf(rA[3], A3, Ab))));
        const float drawB = fmaf(rB[0], B0, fmaf(rB[1], B1, fmaf(rB[2], B2, fmaf(rB[3], B3, Bb))));
        const float dtA = softplus_(drawA);
        const float dtB = softplus_(drawB);
        const float dAA = __expf(dtA * An);
        const float dAB = __expf(dtB * Bn);
        PA *= dAA;
        PB *= dAB;
        hA = fmaf(dAA, hA, dtA * rA[4] * xv[i]);
        hB = fmaf(dAB, hB, dtB * rB[4] * xv[j]);
    }
    Pa[((size_t)bkA * NCH + c)  * 128 + d] = PA;
    Hl[((size_t)bkA * NCH + c)  * 128 + d] = hA;
    Pa[((size_t)bkB * NCH + c2) * 128 + d] = PB;
    Hl[((size_t)bkB * NCH + c2) * 128 + d] = hB;
}

// ---------------- Scan pass 2: combine chunk summaries ----------------
__global__ __launch_bounds__(128) void k_scan2(const float* __restrict__ Pa,
                                               const float* __restrict__ Hl,
                                               float* __restrict__ H0)
{
    const int bk = blockIdx.x;
    const int d  = threadIdx.x;
    float h = 0.0f;
#pragma unroll 14
    for (int c = 0; c < NCH; ++c) {
        const size_t o = ((size_t)bk * NCH + c) * 128 + d;
        H0[o] = h;
        h = fmaf(Pa[o], h, Hl[o]);
    }
}

// ---------------- Scan pass 3a: dirs 0+1 interleaved, plain store ----------------
__global__ __launch_bounds__(128) void k_scan3a(const float* __restrict__ xc,
                                                const float* __restrict__ xdn,
                                                const float* __restrict__ dtw_g,
                                                const float* __restrict__ dtb_g,
                                                const float* __restrict__ alog,
                                                const float* __restrict__ ds_g,
                                                const float* __restrict__ H0,
                                                float* __restrict__ ysum)
{
    __shared__ float xds[CS * 16];
    const int b = blockIdx.x / NCH;
    const int c = blockIdx.x % NCH;
    const int d = threadIdx.x;
    const int c2 = NCH - 1 - c;
    const int bk0 = b * 4 + 0, bk1 = b * 4 + 1;
    const int l0a = c * CS;

    const float* xcb  = &xc[(size_t)b * LL * 128];
    const float* base = &xdn[(size_t)b * LL * 32];
    float* yb = &ysum[(size_t)b * LL * 128];

    if (d < CS * 4) {
        const int row = d >> 2;
        const int q   = (d & 3) * 4;
        *(float4*)&xds[row * 16 + q] = *(const float4*)&base[(size_t)(l0a + row) * 32 + q];
    }
    __syncthreads();

    float xv[CS];
#pragma unroll
    for (int i = 0; i < CS; ++i) xv[i] = xcb[(size_t)(l0a + i) * 128 + d];

    const float A0 = dtw_g[(0 * 128 + d) * 4 + 0];
    const float A1 = dtw_g[(0 * 128 + d) * 4 + 1];
    const float A2 = dtw_g[(0 * 128 + d) * 4 + 2];
    const float A3 = dtw_g[(0 * 128 + d) * 4 + 3];
    const float Ab = dtb_g[0 * 128 + d];
    const float An = -__expf(alog[0 * 128 + d]);
    const float AD = ds_g[0 * 128 + d];
    const float B0 = dtw_g[(1 * 128 + d) * 4 + 0];
    const float B1 = dtw_g[(1 * 128 + d) * 4 + 1];
    const float B2 = dtw_g[(1 * 128 + d) * 4 + 2];
    const float B3 = dtw_g[(1 * 128 + d) * 4 + 3];
    const float Bb = dtb_g[1 * 128 + d];
    const float Bn = -__expf(alog[1 * 128 + d]);
    const float BD = ds_g[1 * 128 + d];

    float y[CS];
#pragma unroll
    for (int i = 0; i < CS; ++i) y[i] = 0.0f;

    float hA = H0[((size_t)bk0 * NCH + c)  * 128 + d];
    float hB = H0[((size_t)bk1 * NCH + c2) * 128 + d];
#pragma unroll
    for (int i = 0; i < CS; ++i) {
        const int j = CS - 1 - i;
        const float* rA = &xds[i * 16];
        const float* rB = &xds[j * 16 + 8];
        const float drawA = fmaf(rA[0], A0, fmaf(rA[1], A1, fmaf(rA[2], A2, fmaf(rA[3], A3, Ab))));
        const float drawB = fmaf(rB[0], B0, fmaf(rB[1], B1, fmaf(rB[2], B2, fmaf(rB[3], B3, Bb))));
        const float dtA = softplus_(drawA);
        const float dtB = softplus_(drawB);
        const float dAA = __expf(dtA * An);
        const float dAB = __expf(dtB * Bn);
        hA = fmaf(dAA, hA, dtA * rA[4] * xv[i]);
        hB = fmaf(dAB, hB, dtB * rB[4] * xv[j]);
        y[i] += fmaf(hA, rA[5], AD * xv[i]);
        y[j] += fmaf(hB, rB[5], BD * xv[j]);
    }
#pragma unroll
    for (int i = 0; i < CS; ++i)
        yb[(size_t)(l0a + i) * 128 + d] = y[i];
}

// ---------------- Scan pass 3b + final: dirs 2+3, read 3a's ysum, LN+gate+mean ----------------
#define YPAD 129
__global__ __launch_bounds__(128) void k_scan3bf(const float* __restrict__ xc,
                                                 const float* __restrict__ xdn,
                                                 const float* __restrict__ dtw_g,
                                                 const float* __restrict__ dtb_g,
                                                 const float* __restrict__ alog,
                                                 const float* __restrict__ ds_g,
                                                 const float* __restrict__ H0,
                                                 const float* __restrict__ ysum,
                                                 const float* __restrict__ zs,
                                                 const float* __restrict__ onw,
                                                 const float* __restrict__ onb,
                                                 float* __restrict__ out)
{
    __shared__ float xds[CS * 16];
    __shared__ float yl[CS * YPAD];
    __shared__ float muS[CS];
    __shared__ float rsS[CS];
    const int b = blockIdx.x / NCH;
    const int c = blockIdx.x % NCH;
    const int d = threadIdx.x;
    const int c2 = NCH - 1 - c;
    const int bk2 = b * 4 + 2, bk3 = b * 4 + 3;
    const int l0a = c * CS;

    const float* xcb  = &xc[(size_t)b * LL * 128];
    const float* base = &xdn[(size_t)b * LL * 32];
    const float* yb   = &ysum[(size_t)b * LL * 128];
    const float* zb   = &zs[(size_t)b * LL * 128];

    if (d < CS * 4) {
        const int row = d >> 2;
        const int q   = (d & 3) * 4;
        const int l   = l0a + row;
        const int prow = (l % HHH) * WWW + (l / HHH);
        *(float4*)&xds[row * 16 + q] = *(const float4*)&base[(size_t)prow * 32 + 16 + q];
    }
    __syncthreads();

    int pj[CS];
#pragma unroll
    for (int i = 0; i < CS; ++i) {
        const int l = l0a + i;
        pj[i] = (l % HHH) * WWW + (l / HHH);
    }
    float xv[CS];
#pragma unroll
    for (int i = 0; i < CS; ++i) xv[i] = xcb[(size_t)pj[i] * 128 + d];

    const float A0 = dtw_g[(2 * 128 + d) * 4 + 0];
    const float A1 = dtw_g[(2 * 128 + d) * 4 + 1];
    const float A2 = dtw_g[(2 * 128 + d) * 4 + 2];
    const float A3 = dtw_g[(2 * 128 + d) * 4 + 3];
    const float Ab = dtb_g[2 * 128 + d];
    const float An = -__expf(alog[2 * 128 + d]);
    const float AD = ds_g[2 * 128 + d];
    const float B0 = dtw_g[(3 * 128 + d) * 4 + 0];
    const float B1 = dtw_g[(3 * 128 + d) * 4 + 1];
    const float B2 = dtw_g[(3 * 128 + d) * 4 + 2];
    const float B3 = dtw_g[(3 * 128 + d) * 4 + 3];
    const float Bb = dtb_g[3 * 128 + d];
    const float Bn = -__expf(alog[3 * 128 + d]);
    const float BD = ds_g[3 * 128 + d];

    float y[CS];
#pragma unroll
    for (int i = 0; i < CS; ++i) y[i] = 0.0f;

    float hA = H0[((size_t)bk2 * NCH + c)  * 128 + d];
    float hB = H0[((size_t)bk3 * NCH + c2) * 128 + d];
#pragma unroll
    for (int i = 0; i < CS; ++i) {
        const int j = CS - 1 - i;
        const float* rA = &xds[i * 16];
        const float* rB = &xds[j * 16 + 8];
        const float drawA = fmaf(rA[0], A0, fmaf(rA[1], A1, fmaf(rA[2], A2, fmaf(rA[3], A3, Ab))));
        const float drawB = fmaf(rB[0], B0, fmaf(rB[1], B1, fmaf(rB[2], B2, fmaf(rB[3], B3, Bb))));
        const float dtA = softplus_(drawA);
        const float dtB = softplus_(drawB);
        const float dAA = __expf(dtA * An);
        const float dAB = __expf(dtB * Bn);
        hA = fmaf(dAA, hA, dtA * rA[4] * xv[i]);
        hB = fmaf(dAB, hB, dtB * rB[4] * xv[j]);
        y[i] += fmaf(hA, rA[5], AD * xv[i]);
        y[j] += fmaf(hB, rB[5], BD * xv[j]);
    }

    // add k0+k1 contribution (scan3a's store): complete 4-direction sum; spill to LDS
#pragma unroll
    for (int i = 0; i < CS; ++i) {
        y[i] += yb[(size_t)pj[i] * 128 + d];
        yl[i * YPAD + d] = y[i];
    }
    __syncthreads();

    // parallel LN stats: 8 lanes per position, each sums a 16-wide d-slice
    {
        const int pos = d >> 3;
        const int q   = d & 7;
        const float* yrow = &yl[pos * YPAD + q * 16];
        float sm = 0.0f;
#pragma unroll
        for (int j = 0; j < 16; ++j) sm += yrow[j];
        sm += __shfl_xor(sm, 1, 64);
        sm += __shfl_xor(sm, 2, 64);
        sm += __shfl_xor(sm, 4, 64);
        const float mu = sm * (1.0f / 128.0f);
        float sq = 0.0f;
#pragma unroll
        for (int j = 0; j < 16; ++j) { const float t = yrow[j] - mu; sq = fmaf(t, t, sq); }
        sq += __shfl_xor(sq, 1, 64);
        sq += __shfl_xor(sq, 2, 64);
        sq += __shfl_xor(sq, 4, 64);
        if (q == 0) {
            muS[pos] = mu;
            rsS[pos] = rsqrtf(sq * (1.0f / 128.0f) + 1e-5f);
        }
    }
    __syncthreads();

    // normalize from registers, gate, accumulate spatial mean
    const float wd = onw[d];
    const float bd = onb[d];
    float acc = 0.0f;
#pragma unroll
    for (int i = 0; i < CS; ++i) {
        const float yn = fmaf((y[i] - muS[i]) * rsS[i], wd, bd);
        acc = fmaf(yn, zb[(size_t)pj[i] * 128 + d], acc);
    }
    atomicAdd(&out[b * 128 + d], acc * (1.0f / (float)LL));
}

extern "C" void kernel_launch(void* const* d_in, const int* in_sizes, int n_in,
                              void* d_out, int out_size, void* d_ws, size_t ws_size,
                              hipStream_t stream)
{
    const float* x     = (const float*)d_in[0];
    const float* ipw   = (const float*)d_in[1];
    const float* cw    = (const float*)d_in[2];
    const float* cb    = (const float*)d_in[3];
    const float* xpw   = (const float*)d_in[4];
    const float* dtw   = (const float*)d_in[5];
    const float* dtb   = (const float*)d_in[6];
    const float* alog  = (const float*)d_in[7];
    const float* dsg   = (const float*)d_in[8];
    const float* onw   = (const float*)d_in[9];
    const float* onb   = (const float*)d_in[10];
    float* out = (float*)d_out;

    float* ws   = (float*)d_ws;
    float* xi   = ws + OFF_XI;     // becomes ysum
    float* zs   = ws + OFF_ZS;
    float* xc   = ws + OFF_XC;
    float* xdn  = ws + OFF_XDN;
    float* Pa   = ws + OFF_PA;
    float* Hl   = ws + OFF_HL;
    float* H0   = ws + OFF_H0;
    float* cwT  = ws + OFF_CWT;
    float* ysum = xi;
    short* Whi = (short*)(ws + OFF_XC);
    short* Wlo = (short*)(ws + OFF_XC + 16384);

    hipMemsetAsync(out, 0, (size_t)out_size * 4, stream);

    k_wsplit<<<128, 256, 0, stream>>>(ipw, cw, Whi, Wlo, cwT);
    k_inproj<<<784, 256, 0, stream>>>(x, Whi, Wlo, xi, zs);

    k_conv4<<<1568, 256, 0, stream>>>(xi, cwT, cb, xc);

    k_projN<<<BB * 49, 256, 0, stream>>>(xc, xpw, xdn);

    k_scan1m<<<2 * BB * NCH, 128, 0, stream>>>(xc, xdn, dtw, dtb, alog, Pa, Hl);
    k_scan2<<<BB * KK, 128, 0, stream>>>(Pa, Hl, H0);
    k_scan3a<<<BB * NCH, 128, 0, stream>>>(xc, xdn, dtw, dtb, alog, dsg, H0, ysum);
    k_scan3bf<<<BB * NCH, 128, 0, stream>>>(xc, xdn, dtw, dtb, alog, dsg, H0, ysum,
                                            zs, onw, onb, out);
}